// Round 1
// baseline (318.003 us; speedup 1.0000x reference)
//
#include <hip/hip_runtime.h>

// Problem constants
#define HW 65536            // 256*256
#define GROUPS (HW / 4)     // float4 groups per plane = 16384
#define NMASK_CH 9
#define NKP_CH 23
#define NPARTS 8
#define NB 32

__device__ __forceinline__ void f4add(float4& a, const float4 b) {
    a.x += b.x; a.y += b.y; a.z += b.z; a.w += b.w;
}

// ---------------------------------------------------------------------------
// Mask stats: grid (4 chunks, 8 parts, 32 batches), block 256.
// Each thread handles 16 float4 groups of one (b, part) plane (channel 1+p).
// Accumulates count / sum-of-h / sum-of-w (exact int32) per (b,p).
// ---------------------------------------------------------------------------
__global__ __launch_bounds__(256) void mask_stats_kernel(
    const float* __restrict__ masks, int* __restrict__ stats) {
    const int b = blockIdx.z, p = blockIdx.y, chunk = blockIdx.x;
    const float4* plane =
        (const float4*)(masks + ((size_t)b * NMASK_CH + (1 + p)) * HW);
    int cnt = 0, sx = 0, sy = 0;
    const int g0 = chunk * 4096 + threadIdx.x;
#pragma unroll
    for (int j = 0; j < 16; ++j) {
        const int g = g0 + j * 256;
        const float4 v = plane[g];
        const int base = g * 4;
        const int h = base >> 8, w0 = base & 255;
        if (v.x > 0.5f) { cnt++; sx += h; sy += w0; }
        if (v.y > 0.5f) { cnt++; sx += h; sy += w0 + 1; }
        if (v.z > 0.5f) { cnt++; sx += h; sy += w0 + 2; }
        if (v.w > 0.5f) { cnt++; sx += h; sy += w0 + 3; }
    }
    // wave (64-lane) reduction
#pragma unroll
    for (int off = 32; off; off >>= 1) {
        cnt += __shfl_down(cnt, off);
        sx  += __shfl_down(sx, off);
        sy  += __shfl_down(sy, off);
    }
    __shared__ int sh[3];
    if (threadIdx.x < 3) sh[threadIdx.x] = 0;
    __syncthreads();
    if ((threadIdx.x & 63) == 0) {
        atomicAdd(&sh[0], cnt);
        atomicAdd(&sh[1], sx);
        atomicAdd(&sh[2], sy);
    }
    __syncthreads();
    if (threadIdx.x < 3)
        atomicAdd(&stats[(b * NPARTS + p) * 3 + threadIdx.x], sh[threadIdx.x]);
}

// ---------------------------------------------------------------------------
// Keypoint part stats: grid (32 chunks, 32 batches), block 256.
// Each thread handles 2 float4 pixel-groups; per group reads all 23 channels,
// forms the 8 part sums, thresholds at 0.3, accumulates per-part integrals.
// ---------------------------------------------------------------------------
__global__ __launch_bounds__(256) void kp_stats_kernel(
    const float* __restrict__ kp, int* __restrict__ stats) {
    const int b = blockIdx.y, chunk = blockIdx.x;
    const float4* kb = (const float4*)(kp + (size_t)b * NKP_CH * HW);

    int cnt[NPARTS], sx[NPARTS], sy[NPARTS];
#pragma unroll
    for (int p = 0; p < NPARTS; ++p) { cnt[p] = 0; sx[p] = 0; sy[p] = 0; }

#pragma unroll
    for (int j = 0; j < 2; ++j) {
        const int g = chunk * 512 + j * 256 + threadIdx.x;
        float4 s0, s1, s2, s3, s4, s5, s6, s7, v;
#define LD(K) kb[(K) * GROUPS + g]
        s0 = LD(0);
        v = LD(1); f4add(s0, v);
        v = LD(2); f4add(s0, v);
        v = LD(3); f4add(s0, v);
        v = LD(4); f4add(s0, v);
        v = LD(5); s1 = v; s2 = v;
        v = LD(6); f4add(s1, v); s3 = v;
        v = LD(7); f4add(s2, v);
        v = LD(8); f4add(s3, v);
        v = LD(9); f4add(s2, v);
        v = LD(10); f4add(s3, v);
        v = LD(11); f4add(s1, v); s4 = v;
        v = LD(12); f4add(s1, v); s5 = v;
        v = LD(13); f4add(s4, v);
        v = LD(14); f4add(s5, v);
        v = LD(15); f4add(s4, v); s6 = v;
        v = LD(16); f4add(s5, v); s7 = v;
        v = LD(17); f4add(s6, v);
        v = LD(18); f4add(s6, v);
        v = LD(19); f4add(s6, v);
        v = LD(20); f4add(s7, v);
        v = LD(21); f4add(s7, v);
        v = LD(22); f4add(s7, v);
#undef LD
        const int base = g * 4;
        const int h = base >> 8, w0 = base & 255;
#define TALLY(P, S)                                           \
        if ((S).x > 0.3f) { cnt[P]++; sx[P] += h; sy[P] += w0; }     \
        if ((S).y > 0.3f) { cnt[P]++; sx[P] += h; sy[P] += w0 + 1; } \
        if ((S).z > 0.3f) { cnt[P]++; sx[P] += h; sy[P] += w0 + 2; } \
        if ((S).w > 0.3f) { cnt[P]++; sx[P] += h; sy[P] += w0 + 3; }
        TALLY(0, s0) TALLY(1, s1) TALLY(2, s2) TALLY(3, s3)
        TALLY(4, s4) TALLY(5, s5) TALLY(6, s6) TALLY(7, s7)
#undef TALLY
    }

    // wave reduction of 24 values
#pragma unroll
    for (int p = 0; p < NPARTS; ++p) {
#pragma unroll
        for (int off = 32; off; off >>= 1) {
            cnt[p] += __shfl_down(cnt[p], off);
            sx[p]  += __shfl_down(sx[p], off);
            sy[p]  += __shfl_down(sy[p], off);
        }
    }
    __shared__ int sh[NPARTS * 3];
    if (threadIdx.x < NPARTS * 3) sh[threadIdx.x] = 0;
    __syncthreads();
    if ((threadIdx.x & 63) == 0) {
#pragma unroll
        for (int p = 0; p < NPARTS; ++p) {
            atomicAdd(&sh[p * 3 + 0], cnt[p]);
            atomicAdd(&sh[p * 3 + 1], sx[p]);
            atomicAdd(&sh[p * 3 + 2], sy[p]);
        }
    }
    __syncthreads();
    if (threadIdx.x < NPARTS * 3) {
        // kp section of stats starts at 32*8*3 = 768
        atomicAdd(&stats[768 + b * NPARTS * 3 + threadIdx.x], sh[threadIdx.x]);
    }
}

// ---------------------------------------------------------------------------
// Finisher: 1 block × 256 threads; thread t -> (b = t>>3, p = t&7).
// Centers use fp32 division (matches reference rounding); loss summed in
// double; scalar written by thread 0.
// ---------------------------------------------------------------------------
__global__ __launch_bounds__(256) void finish_kernel(
    const int* __restrict__ stats, float* __restrict__ out) {
    const int t = threadIdx.x;
    const int cm  = stats[t * 3 + 0];
    const int sxm = stats[t * 3 + 1];
    const int sym = stats[t * 3 + 2];
    const int ck  = stats[768 + t * 3 + 0];
    const int sxk = stats[768 + t * 3 + 1];
    const int syk = stats[768 + t * 3 + 2];

    const float cxm = (cm > 0 && sxm > 0) ? (float)sxm / (float)cm : 0.0f;
    const float cym = (cm > 0 && sym > 0) ? (float)sym / (float)cm : 0.0f;
    const float cxk = (ck > 0 && sxk > 0) ? (float)sxk / (float)ck : 0.0f;
    const float cyk = (ck > 0 && syk > 0) ? (float)syk / (float)ck : 0.0f;

    const bool code = (cxm == 0.0f) || (cym == 0.0f) ||
                      (cxk == 0.0f) || (cyk == 0.0f);
    double num = 0.0, nv = 0.0;
    if (!code) {
        const double dx = (double)cxm - (double)cxk;
        const double dy = (double)cym - (double)cyk;
        num = dx * dx + dy * dy;
        nv = 1.0;
    }
#pragma unroll
    for (int off = 32; off; off >>= 1) {
        num += __shfl_down(num, off);
        nv  += __shfl_down(nv, off);
    }
    __shared__ double sh[8];
    const int wave = t >> 6;
    if ((t & 63) == 0) { sh[wave * 2] = num; sh[wave * 2 + 1] = nv; }
    __syncthreads();
    if (t == 0) {
        const double N = sh[0] + sh[2] + sh[4] + sh[6];
        const double V = sh[1] + sh[3] + sh[5] + sh[7];
        out[0] = (float)(1e-5 * (N / (V * 2.0)));
    }
}

extern "C" void kernel_launch(void* const* d_in, const int* in_sizes, int n_in,
                              void* d_out, int out_size, void* d_ws, size_t ws_size,
                              hipStream_t stream) {
    const float* masks = (const float*)d_in[0];   // (32, 9, 256, 256) fp32
    const float* kp    = (const float*)d_in[1];   // (32, 23, 256, 256) fp32
    float* out = (float*)d_out;
    int* stats = (int*)d_ws;   // [0,768): mask (b,p){cnt,sx,sy}; [768,1536): kp

    hipMemsetAsync(d_ws, 0, 1536 * sizeof(int), stream);
    hipLaunchKernelGGL(mask_stats_kernel, dim3(4, NPARTS, NB), dim3(256), 0,
                       stream, masks, stats);
    hipLaunchKernelGGL(kp_stats_kernel, dim3(32, NB), dim3(256), 0,
                       stream, kp, stats);
    hipLaunchKernelGGL(finish_kernel, dim3(1), dim3(256), 0, stream, stats, out);
}

// Round 2
// 286.164 us; speedup vs baseline: 1.1113x; 1.1113x over previous
//
#include <hip/hip_runtime.h>

// Problem constants
#define HW 65536            // 256*256
#define GROUPS 16384        // float4 groups per plane
#define NMASK_CH 9
#define NKP_CH 23
#define NPARTS 8
#define NB 32

// Workspace layout (ints):
//   [0, 768)            mask stats:  (b*8+p)*3 + {cnt,sx,sy}   (one block per plane)
//   [768, 768+24576)    kp partials: 768 + (b*32+c)*24 + p*3 + {cnt,sx,sy}
#define KP_OFF 768

typedef float vf4 __attribute__((ext_vector_type(4)));

__device__ __forceinline__ vf4 ntload(const float* p) {
    return __builtin_nontemporal_load((const vf4*)p);
}

// ---------------------------------------------------------------------------
// Fused stats kernel, grid = 1280 blocks x 256 threads.
//   blocks [0,256):     mask plane (b = bid>>3, p = bid&7), 64 float4/thread
//   blocks [256,1280):  kp chunk  (b = id>>5,  c = id&31), 2 float4/thread,
//                       all 23 channels -> 8 part sums -> 24 integrals
// Per-block partials written to ws; no atomics, no zero-init needed.
// ---------------------------------------------------------------------------
__global__ __launch_bounds__(256) void stats_kernel(
    const float* __restrict__ masks, const float* __restrict__ kp,
    int* __restrict__ stats) {
    const int tid = threadIdx.x;
    const int bid = blockIdx.x;
    const int wave = tid >> 6;
    __shared__ int sh[4][NPARTS * 3];

    if (bid < 256) {
        // ---- mask path ----
        const int b = bid >> 3, p = bid & 7;
        const float* plane = masks + ((size_t)b * NMASK_CH + 1 + p) * HW;
        int cnt = 0, sx = 0, sy = 0;
#pragma unroll 8
        for (int j = 0; j < 64; ++j) {
            const int g = tid + j * 256;
            const vf4 v = ntload(plane + (size_t)g * 4);
            const int base = g * 4;
            const int h = base >> 8, w0 = base & 255;
            if (v.x > 0.5f) { cnt++; sx += h; sy += w0; }
            if (v.y > 0.5f) { cnt++; sx += h; sy += w0 + 1; }
            if (v.z > 0.5f) { cnt++; sx += h; sy += w0 + 2; }
            if (v.w > 0.5f) { cnt++; sx += h; sy += w0 + 3; }
        }
#pragma unroll
        for (int off = 32; off; off >>= 1) {
            cnt += __shfl_down(cnt, off);
            sx  += __shfl_down(sx, off);
            sy  += __shfl_down(sy, off);
        }
        if ((tid & 63) == 0) {
            sh[wave][0] = cnt; sh[wave][1] = sx; sh[wave][2] = sy;
        }
        __syncthreads();
        if (tid < 3)
            stats[bid * 3 + tid] =
                sh[0][tid] + sh[1][tid] + sh[2][tid] + sh[3][tid];
    } else {
        // ---- keypoint path ----
        const int id = bid - 256;
        const int b = id >> 5, c = id & 31;
        const float* kb = kp + (size_t)b * NKP_CH * HW;

        int cnt[NPARTS], sx[NPARTS], sy[NPARTS];
#pragma unroll
        for (int p = 0; p < NPARTS; ++p) { cnt[p] = 0; sx[p] = 0; sy[p] = 0; }

#pragma unroll
        for (int j = 0; j < 2; ++j) {
            const int g = c * 512 + j * 256 + tid;
            vf4 s0, s1, s2, s3, s4, s5, s6, s7, v;
#define LD(K) ntload(kb + (size_t)((K) * GROUPS + g) * 4)
            s0 = LD(0);
            v = LD(1); s0 += v;
            v = LD(2); s0 += v;
            v = LD(3); s0 += v;
            v = LD(4); s0 += v;
            v = LD(5); s1 = v; s2 = v;
            v = LD(6); s1 += v; s3 = v;
            v = LD(7); s2 += v;
            v = LD(8); s3 += v;
            v = LD(9); s2 += v;
            v = LD(10); s3 += v;
            v = LD(11); s1 += v; s4 = v;
            v = LD(12); s1 += v; s5 = v;
            v = LD(13); s4 += v;
            v = LD(14); s5 += v;
            v = LD(15); s4 += v; s6 = v;
            v = LD(16); s5 += v; s7 = v;
            v = LD(17); s6 += v;
            v = LD(18); s6 += v;
            v = LD(19); s6 += v;
            v = LD(20); s7 += v;
            v = LD(21); s7 += v;
            v = LD(22); s7 += v;
#undef LD
            const int base = g * 4;
            const int h = base >> 8, w0 = base & 255;
#define TALLY(P, S)                                                  \
            if ((S).x > 0.3f) { cnt[P]++; sx[P] += h; sy[P] += w0; }     \
            if ((S).y > 0.3f) { cnt[P]++; sx[P] += h; sy[P] += w0 + 1; } \
            if ((S).z > 0.3f) { cnt[P]++; sx[P] += h; sy[P] += w0 + 2; } \
            if ((S).w > 0.3f) { cnt[P]++; sx[P] += h; sy[P] += w0 + 3; }
            TALLY(0, s0) TALLY(1, s1) TALLY(2, s2) TALLY(3, s3)
            TALLY(4, s4) TALLY(5, s5) TALLY(6, s6) TALLY(7, s7)
#undef TALLY
        }

#pragma unroll
        for (int p = 0; p < NPARTS; ++p) {
#pragma unroll
            for (int off = 32; off; off >>= 1) {
                cnt[p] += __shfl_down(cnt[p], off);
                sx[p]  += __shfl_down(sx[p], off);
                sy[p]  += __shfl_down(sy[p], off);
            }
        }
        if ((tid & 63) == 0) {
#pragma unroll
            for (int p = 0; p < NPARTS; ++p) {
                sh[wave][p * 3 + 0] = cnt[p];
                sh[wave][p * 3 + 1] = sx[p];
                sh[wave][p * 3 + 2] = sy[p];
            }
        }
        __syncthreads();
        if (tid < NPARTS * 3)
            stats[KP_OFF + id * 24 + tid] =
                sh[0][tid] + sh[1][tid] + sh[2][tid] + sh[3][tid];
    }
}

// ---------------------------------------------------------------------------
// Finisher: 1 block x 256 threads; thread t -> (b = t>>3, p = t&7).
// Sums the 32 kp chunk-partials, replays the reference's fp32 divisions,
// reduces the loss in double, writes the scalar.
// ---------------------------------------------------------------------------
__global__ __launch_bounds__(256) void finish_kernel(
    const int* __restrict__ stats, float* __restrict__ out) {
    const int t = threadIdx.x;
    const int b = t >> 3, p = t & 7;

    const int cm  = stats[t * 3 + 0];
    const int sxm = stats[t * 3 + 1];
    const int sym = stats[t * 3 + 2];

    int ck = 0, sxk = 0, syk = 0;
#pragma unroll
    for (int c = 0; c < 32; ++c) {
        const int base = KP_OFF + (b * 32 + c) * 24 + p * 3;
        ck  += stats[base + 0];
        sxk += stats[base + 1];
        syk += stats[base + 2];
    }

    const float cxm = (cm > 0 && sxm > 0) ? (float)sxm / (float)cm : 0.0f;
    const float cym = (cm > 0 && sym > 0) ? (float)sym / (float)cm : 0.0f;
    const float cxk = (ck > 0 && sxk > 0) ? (float)sxk / (float)ck : 0.0f;
    const float cyk = (ck > 0 && syk > 0) ? (float)syk / (float)ck : 0.0f;

    const bool code = (cxm == 0.0f) || (cym == 0.0f) ||
                      (cxk == 0.0f) || (cyk == 0.0f);
    double num = 0.0, nv = 0.0;
    if (!code) {
        const double dx = (double)cxm - (double)cxk;
        const double dy = (double)cym - (double)cyk;
        num = dx * dx + dy * dy;
        nv = 1.0;
    }
#pragma unroll
    for (int off = 32; off; off >>= 1) {
        num += __shfl_down(num, off);
        nv  += __shfl_down(nv, off);
    }
    __shared__ double sh[8];
    const int wave = t >> 6;
    if ((t & 63) == 0) { sh[wave * 2] = num; sh[wave * 2 + 1] = nv; }
    __syncthreads();
    if (t == 0) {
        const double N = sh[0] + sh[2] + sh[4] + sh[6];
        const double V = sh[1] + sh[3] + sh[5] + sh[7];
        out[0] = (float)(1e-5 * (N / (V * 2.0)));
    }
}

extern "C" void kernel_launch(void* const* d_in, const int* in_sizes, int n_in,
                              void* d_out, int out_size, void* d_ws, size_t ws_size,
                              hipStream_t stream) {
    const float* masks = (const float*)d_in[0];   // (32, 9, 256, 256) fp32
    const float* kp    = (const float*)d_in[1];   // (32, 23, 256, 256) fp32
    float* out = (float*)d_out;
    int* stats = (int*)d_ws;

    hipLaunchKernelGGL(stats_kernel, dim3(1280), dim3(256), 0, stream,
                       masks, kp, stats);
    hipLaunchKernelGGL(finish_kernel, dim3(1), dim3(256), 0, stream, stats, out);
}